// Round 10
// baseline (239.260 us; speedup 1.0000x reference)
//
#include <hip/hip_runtime.h>
#include <math.h>

#define N_CVS   4096
#define FEAT    128
#define BATCH   8192
#define KNN_K   15
#define E_MIN_F 0.34867844f

typedef __attribute__((ext_vector_type(8))) short bf16x8;
typedef __attribute__((ext_vector_type(4))) float f32x4;
typedef __attribute__((ext_vector_type(4))) unsigned int u32x4;

// ------- fused fp32->bf16 (RNE) + row norms (16 threads/row, shfl reduce) ---
__global__ void cvtnorm_kernel(const float* __restrict__ x, const float* __restrict__ cvs,
                               unsigned short* __restrict__ xb, unsigned short* __restrict__ cb,
                               float* __restrict__ x2, float* __restrict__ c2) {
    size_t tid = (size_t)blockIdx.x * 256 + threadIdx.x;
    size_t f = tid * 8;
    const float* src; unsigned short* dst; float* ndst; size_t row;
    if (f < (size_t)BATCH * FEAT) { src = x + f; dst = xb + f; row = f >> 7; ndst = x2 + row; }
    else {
        size_t g = f - (size_t)BATCH * FEAT;
        src = cvs + g; dst = cb + g; row = g >> 7; ndst = c2 + row;
    }
    float4 v0 = ((const float4*)src)[0];
    float4 v1 = ((const float4*)src)[1];
    float vv[8] = {v0.x, v0.y, v0.z, v0.w, v1.x, v1.y, v1.z, v1.w};
    bf16x8 o;
    float s = 0.f;
    #pragma unroll
    for (int i = 0; i < 8; ++i) {
        unsigned u = __float_as_uint(vv[i]);
        o[i] = (short)((u + 0x7fffu + ((u >> 16) & 1u)) >> 16);   // RNE
        s += vv[i] * vv[i];
    }
    *(bf16x8*)dst = o;
    #pragma unroll
    for (int off = 1; off < 16; off <<= 1) s += __shfl_xor(s, off, 64);
    if ((threadIdx.x & 15) == 0) *ndst = s;
}

// ------ d2 = max(x2 + c2 - 2 x.cv^T, 0), bf16 MFMA; emits per-chunk row mins
#define LROW 272
__global__ __launch_bounds__(256) void mfma_d2_kernel(
        const unsigned short* __restrict__ xb, const unsigned short* __restrict__ cb,
        const float* __restrict__ x2g, const float* __restrict__ c2g,
        float* __restrict__ d2, float* __restrict__ rowmin) {
    __shared__ __align__(16) char lds[2 * 128 * LROW];   // 68 KB
    __shared__ unsigned int rmin[128];
    char* Al = lds;
    char* Bl = lds + 128 * LROW;
    const int bi = blockIdx.y * 128;
    const int bj = blockIdx.x * 128;
    const int t  = threadIdx.x;

    if (t < 128) rmin[t] = 0xffffffffu;
    #pragma unroll
    for (int i = 0; i < 8; ++i) {
        int f = t + i * 256;
        int row = f >> 4, g = f & 15;
        ulonglong2 va = *(const ulonglong2*)((const char*)(xb + (size_t)(bi + row) * FEAT) + g * 16);
        *(ulonglong2*)(Al + row * LROW + g * 16) = va;
        ulonglong2 vb = *(const ulonglong2*)((const char*)(cb + (size_t)(bj + row) * FEAT) + g * 16);
        *(ulonglong2*)(Bl + row * LROW + g * 16) = vb;
    }
    __syncthreads();

    const int lane = t & 63;
    const int wave = t >> 6;
    const int wr = (wave >> 1) * 64;
    const int wc = (wave & 1) * 64;
    const int l15 = lane & 15, quad = lane >> 4;

    f32x4 acc[4][4];
    #pragma unroll
    for (int i = 0; i < 4; ++i)
        #pragma unroll
        for (int j = 0; j < 4; ++j)
            acc[i][j] = (f32x4){0.f, 0.f, 0.f, 0.f};

    #pragma unroll
    for (int ks = 0; ks < 4; ++ks) {
        bf16x8 a[4], b[4];
        #pragma unroll
        for (int s = 0; s < 4; ++s) {
            a[s] = *(const bf16x8*)(Al + (wr + s * 16 + l15) * LROW + ks * 64 + quad * 16);
            b[s] = *(const bf16x8*)(Bl + (wc + s * 16 + l15) * LROW + ks * 64 + quad * 16);
        }
        #pragma unroll
        for (int si = 0; si < 4; ++si)
            #pragma unroll
            for (int sj = 0; sj < 4; ++sj)
                acc[si][sj] = __builtin_amdgcn_mfma_f32_16x16x32_bf16(a[si], b[sj], acc[si][sj], 0, 0, 0);
    }

    #pragma unroll
    for (int si = 0; si < 4; ++si) {
        #pragma unroll
        for (int r = 0; r < 4; ++r) {
            int mloc = wr + si * 16 + quad * 4 + r;
            int m = bi + mloc;
            float xv = x2g[m];
            float* orow = d2 + (size_t)m * N_CVS + bj + wc;
            float mn = INFINITY;
            #pragma unroll
            for (int sj = 0; sj < 4; ++sj) {
                int nloc = sj * 16 + l15;
                float v = xv + c2g[bj + wc + nloc] - 2.0f * acc[si][sj][r];
                v = fmaxf(v, 0.0f);
                mn = fminf(mn, v);
                orow[nloc] = v;
            }
            // min across the 16 lanes of this quad (masks 1..8 stay in-quad)
            #pragma unroll
            for (int off = 1; off < 16; off <<= 1)
                mn = fminf(mn, __shfl_xor(mn, off, 64));
            if (l15 == 0)
                atomicMin(&rmin[mloc], __float_as_uint(mn));  // d2>=0: uint order ok
        }
    }
    __syncthreads();
    if (t < 128)
        rowmin[(size_t)(bi + t) * 32 + blockIdx.x] = __uint_as_float(rmin[t]);
}

// ---------------- top-15 per row via producer chunk-mins --------------------
// T = 15th smallest of the 32 chunk-mins: each chunk-min is an actual row
// value (distinct col) -> >=15 values <= T -> rank-15 <= T. Only chunks with
// min <= T can hold candidates; candidates = values <= T (always >=15).
// Exact u64-key selection preserves jax.lax.top_k tie semantics.
__global__ __launch_bounds__(256) void topk_kernel(const float* __restrict__ d2,
                                                   const float* __restrict__ rowmin,
                                                   int* __restrict__ knn) {
    __shared__ unsigned long long cand[4][64];
    const int wv   = threadIdx.x >> 6;
    const int wid  = blockIdx.x * 4 + wv;
    const int lane = threadIdx.x & 63;
    const float* row = d2 + (size_t)wid * N_CVS;

    float cm = rowmin[(size_t)wid * 32 + (lane & 31)];   // lanes 32-63 duplicate
    float s = (lane < 32) ? cm : INFINITY;
    #pragma unroll
    for (int k = 2; k <= 64; k <<= 1) {
        #pragma unroll
        for (int j = k >> 1; j > 0; j >>= 1) {
            float o = __shfl_xor(s, j, 64);
            bool lower = ((lane & j) == 0);
            bool asc   = ((lane & k) == 0);
            float lo = fminf(s, o), hi = fmaxf(s, o);
            s = (lower == asc) ? lo : hi;
        }
    }
    float T = __shfl(s, 14, 64);   // 15th smallest chunk-min

    unsigned long long* cbuf = cand[wv];
    int base = 0;
    for (int c = 0; c < 32; ++c) {
        float mc = __shfl(cm, c, 64);
        if (mc <= T) {
            float2 v2 = *(const float2*)(row + c * 128 + lane * 2);
            float vv[2] = {v2.x, v2.y};
            #pragma unroll
            for (int h = 0; h < 2; ++h) {
                bool p = (vv[h] <= T);
                unsigned long long mask = __ballot(p);
                if (p) {
                    int pos = base + __popcll(mask & ((1ULL << lane) - 1ULL));
                    if (pos < 64)
                        cbuf[pos] = ((unsigned long long)__float_as_uint(vv[h]) << 32)
                                  | (unsigned)(c * 128 + lane * 2 + h);
                }
                base += __popcll(mask);
            }
        }
    }
    __builtin_amdgcn_wave_barrier();

    int* outp = knn + wid * KNN_K;
    if (base <= 64) {
        unsigned long long key = (lane < base) ? cbuf[lane] : ~0ULL;
        for (int r = 0; r < KNN_K; ++r) {
            unsigned long long m = key;
            #pragma unroll
            for (int off = 32; off > 0; off >>= 1) {
                unsigned long long o = __shfl_xor(m, off, 64);
                m = (o < m) ? o : m;
            }
            if (lane == 0) outp[r] = (int)(unsigned)(m & 0xffffffffu);
            if (key == m) key = ~0ULL;
        }
    } else {
        // exact fallback: full-row 15-deep insertion scan (rare, data-dependent)
        unsigned long long heap[15];
        #pragma unroll
        for (int k = 0; k < 15; ++k) heap[k] = ~0ULL;
        for (int i = 0; i < 16; ++i) {
            int j0 = lane * 4 + i * 256;
            float4 f4 = *(const float4*)(row + j0);
            float vv[4] = {f4.x, f4.y, f4.z, f4.w};
            #pragma unroll
            for (int c = 0; c < 4; ++c) {
                unsigned long long key =
                    ((unsigned long long)__float_as_uint(vv[c]) << 32) | (unsigned)(j0 + c);
                if (key < heap[14]) {
                    heap[14] = key;
                    #pragma unroll
                    for (int k = 14; k > 0; --k) {
                        unsigned long long a = heap[k-1], b = heap[k];
                        bool sw = b < a;
                        heap[k-1] = sw ? b : a;
                        heap[k]   = sw ? a : b;
                    }
                }
            }
        }
        for (int r = 0; r < KNN_K; ++r) {
            unsigned long long cd = heap[0];
            unsigned long long m = cd;
            #pragma unroll
            for (int off = 32; off > 0; off >>= 1) {
                unsigned long long o = __shfl_xor(m, off, 64);
                m = (o < m) ? o : m;
            }
            if (lane == 0) outp[r] = (int)(unsigned)(m & 0xffffffffu);
            if (cd == m) {
                #pragma unroll
                for (int k = 0; k < 14; ++k) heap[k] = heap[k+1];
                heap[14] = ~0ULL;
            }
        }
    }
}

// ---------------- visits + cce scatter (cce packed u8, word atomics) --------
__global__ void scatter_kernel(const int* __restrict__ knn, int* __restrict__ visits,
                               unsigned int* __restrict__ cce8) {
    int b = blockIdx.x * 256 + threadIdx.x;
    const int* kr = knn + b * KNN_K;
    int closest = kr[0];
    atomicAdd(&visits[closest], 1);
    size_t base = (size_t)closest * N_CVS;
    #pragma unroll
    for (int k = 0; k < KNN_K; ++k) {
        size_t idx = base + kr[k];
        atomicAdd((int*)&cce8[idx >> 2], 1 << ((idx & 3) * 8));
    }
}

// ---------------- neighbor mask bits: one block per row, 16 elems/thread ----
// enc<=9 integer rule: np computes 0.9f**enc in fp32; 0.9f^10 < E_MIN, so
// enc==10 edges are dropped by the reference (verified absmax 0.0 in R8).
// conn loaded conditionally (~0.8% density).
__global__ __launch_bounds__(256) void bits_kernel(
        const unsigned int* __restrict__ cce8, const int* __restrict__ visits,
        const float* __restrict__ edges, const float* __restrict__ conn,
        unsigned short* __restrict__ bits16) {
    const int row = blockIdx.x;
    const int t   = threadIdx.x;
    const int vis = visits[row];
    size_t eb = (size_t)row * N_CVS + t * 16;
    f32x4 e[4];
    #pragma unroll
    for (int q = 0; q < 4; ++q) e[q] = ((const f32x4*)(edges + eb))[q];
    u32x4 cw = ((const u32x4*)(cce8 + (size_t)row * 1024))[t];

    unsigned pre = 0;
    #pragma unroll
    for (int q = 0; q < 4; ++q) {
        #pragma unroll
        for (int s = 0; s < 4; ++s) {
            int cc = (cw[q] >> (s * 8)) & 0xff;
            float ev = e[q][s];
            float ex = (cc > 0) ? fmaxf(ev, 1.0f) : ev;
            bool p;
            if (ex == 1.0f) {
                p = (vis - cc) <= 9;
            } else if (ex > 0.0f) {
                float enc = fmaxf((float)(vis - cc), 0.0f);
                p = ex * powf(0.9f, enc) >= E_MIN_F;
            } else {
                p = false;
            }
            pre |= (unsigned)p << (q * 4 + s);
        }
    }
    unsigned m = 0;
    #pragma unroll
    for (int q = 0; q < 4; ++q) {
        unsigned pn = (pre >> (q * 4)) & 0xfu;
        if (pn) {
            f32x4 cv = ((const f32x4*)(conn + eb))[q];
            #pragma unroll
            for (int s = 0; s < 4; ++s)
                if (((pn >> s) & 1u) && (cv[s] < 1.0f)) m |= 1u << (q * 4 + s);
        }
    }
    bits16[(size_t)row * 256 + t] = (unsigned short)m;
}

// ---------------- per-sample masked soft-min loss -> partial[b] -------------
__global__ void loss_kernel(const float* __restrict__ d2,
                            const unsigned long long* __restrict__ bits,
                            const int* __restrict__ labels, float* __restrict__ partial) {
    int wid  = blockIdx.x * 4 + (threadIdx.x >> 6);
    int lane = threadIdx.x & 63;
    int l = labels[wid];
    const unsigned long long* rb = bits + (size_t)l * 64;
    const float* row = d2 + (size_t)wid * N_CVS;
    float se = 0.f, sed = 0.f;
    unsigned long long w = rb[lane];
    while (w) {
        int c = __builtin_ctzll(w);
        w &= w - 1;
        int j = lane * 64 + c;
        float d = row[j];
        if (d > 0.f) {
            float ee = __expf(-0.001f * d);
            se += ee; sed += ee * d;
        }
    }
    #pragma unroll
    for (int off = 32; off > 0; off >>= 1) {
        se  += __shfl_xor(se,  off, 64);
        sed += __shfl_xor(sed, off, 64);
    }
    if (lane == 0) {
        float dpos = row[l];
        float wsum = se > 0.f ? sed / se : 0.f;
        float mu = dpos - wsum;
        partial[wid] = (mu > 0.f) ? mu : 0.f;
    }
}

// ---------------- final reduction: sum(partial)/BATCH -> out ----------------
__global__ void reduce_kernel(const float* __restrict__ partial, float* __restrict__ out) {
    int t = threadIdx.x;
    float s = 0.f;
    #pragma unroll
    for (int i = 0; i < BATCH / 256; ++i) s += partial[t + i * 256];
    #pragma unroll
    for (int off = 32; off > 0; off >>= 1) s += __shfl_xor(s, off, 64);
    __shared__ float wsum[4];
    if ((t & 63) == 0) wsum[t >> 6] = s;
    __syncthreads();
    if (t == 0) out[0] = (wsum[0] + wsum[1] + wsum[2] + wsum[3]) * (1.0f / BATCH);
}

extern "C" void kernel_launch(void* const* d_in, const int* in_sizes, int n_in,
                              void* d_out, int out_size, void* d_ws, size_t ws_size,
                              hipStream_t stream) {
    const float* x      = (const float*)d_in[0];
    const float* cvs    = (const float*)d_in[1];
    const float* edges  = (const float*)d_in[2];
    const float* conn   = (const float*)d_in[3];
    const int*   labels = (const int*)d_in[4];

    char* p = (char*)d_ws;
    float* d2 = (float*)p;                  p += (size_t)BATCH * N_CVS * 4;   // 128 MB
    int* knn  = (int*)p;                    p += (size_t)BATCH * KNN_K * 4;   // 480 KB
    int* visits = (int*)p;                  p += (size_t)N_CVS * 4;           // 16 KB
    unsigned int* cce8 = (unsigned int*)p;  p += (size_t)N_CVS * N_CVS;       // 16 MB (u8)
    unsigned long long* bits = (unsigned long long*)p;
                                            p += (size_t)N_CVS * 64 * 8;      // 2 MB
    float* x2 = (float*)p;                  p += (size_t)BATCH * 4;
    float* c2 = (float*)p;                  p += (size_t)N_CVS * 4;
    unsigned short* xb = (unsigned short*)p; p += (size_t)BATCH * FEAT * 2;   // 2 MB
    unsigned short* cb = (unsigned short*)p; p += (size_t)N_CVS * FEAT * 2;   // 1 MB
    float* partial = (float*)p;             p += (size_t)BATCH * 4;           // 32 KB
    float* rowmin = (float*)p;              p += (size_t)BATCH * 32 * 4;      // 1 MB

    hipMemsetAsync(visits, 0, (size_t)N_CVS * 4 + (size_t)N_CVS * N_CVS, stream);

    cvtnorm_kernel<<<(BATCH + N_CVS) * FEAT / 8 / 256, 256, 0, stream>>>(x, cvs, xb, cb, x2, c2);
    mfma_d2_kernel<<<dim3(N_CVS / 128, BATCH / 128), 256, 0, stream>>>(xb, cb, x2, c2, d2, rowmin);
    topk_kernel   <<<BATCH / 4, 256, 0, stream>>>(d2, rowmin, knn);
    scatter_kernel<<<BATCH / 256, 256, 0, stream>>>(knn, visits, cce8);
    bits_kernel   <<<N_CVS, 256, 0, stream>>>(
                      cce8, visits, edges, conn, (unsigned short*)bits);
    loss_kernel   <<<BATCH / 4, 256, 0, stream>>>(d2, bits, labels, partial);
    reduce_kernel <<<1, 256, 0, stream>>>(partial, (float*)d_out);
}

// Round 11
// 229.002 us; speedup vs baseline: 1.0448x; 1.0448x over previous
//
#include <hip/hip_runtime.h>
#include <math.h>

#define N_CVS   4096
#define FEAT    128
#define BATCH   8192
#define KNN_K   15
#define E_MIN_F 0.34867844f

typedef __attribute__((ext_vector_type(8))) short bf16x8;
typedef __attribute__((ext_vector_type(4))) float f32x4;
typedef __attribute__((ext_vector_type(4))) unsigned int u32x4;

// ------- fused fp32->bf16 (RNE) + row norms (16 threads/row, shfl reduce) ---
__global__ void cvtnorm_kernel(const float* __restrict__ x, const float* __restrict__ cvs,
                               unsigned short* __restrict__ xb, unsigned short* __restrict__ cb,
                               float* __restrict__ x2, float* __restrict__ c2) {
    size_t tid = (size_t)blockIdx.x * 256 + threadIdx.x;
    size_t f = tid * 8;
    const float* src; unsigned short* dst; float* ndst; size_t row;
    if (f < (size_t)BATCH * FEAT) { src = x + f; dst = xb + f; row = f >> 7; ndst = x2 + row; }
    else {
        size_t g = f - (size_t)BATCH * FEAT;
        src = cvs + g; dst = cb + g; row = g >> 7; ndst = c2 + row;
    }
    float4 v0 = ((const float4*)src)[0];
    float4 v1 = ((const float4*)src)[1];
    float vv[8] = {v0.x, v0.y, v0.z, v0.w, v1.x, v1.y, v1.z, v1.w};
    bf16x8 o;
    float s = 0.f;
    #pragma unroll
    for (int i = 0; i < 8; ++i) {
        unsigned u = __float_as_uint(vv[i]);
        o[i] = (short)((u + 0x7fffu + ((u >> 16) & 1u)) >> 16);   // RNE
        s += vv[i] * vv[i];
    }
    *(bf16x8*)dst = o;
    #pragma unroll
    for (int off = 1; off < 16; off <<= 1) s += __shfl_xor(s, off, 64);
    if ((threadIdx.x & 15) == 0) *ndst = s;
}

// ---------------- d2 = max(x2 + c2 - 2 x.cv^T, 0), bf16 MFMA ----------------
// Epilogue stages the 128x128 f32 tile through LDS (reusing the A/B buffers,
// +4 col pad -> 2-way bank aliasing only) so global stores are coalesced
// dwordx4 (the direct C-layout store was 64 scattered dwords/lane -> 3.6 TB/s).
#define LROW 272
#define TROW 132
__global__ __launch_bounds__(256) void mfma_d2_kernel(
        const unsigned short* __restrict__ xb, const unsigned short* __restrict__ cb,
        const float* __restrict__ x2g, const float* __restrict__ c2g,
        float* __restrict__ d2) {
    __shared__ __align__(16) char lds[2 * 128 * LROW];   // 68 KB
    char* Al = lds;
    char* Bl = lds + 128 * LROW;
    const int bi = blockIdx.y * 128;
    const int bj = blockIdx.x * 128;
    const int t  = threadIdx.x;

    #pragma unroll
    for (int i = 0; i < 8; ++i) {
        int f = t + i * 256;
        int row = f >> 4, g = f & 15;
        ulonglong2 va = *(const ulonglong2*)((const char*)(xb + (size_t)(bi + row) * FEAT) + g * 16);
        *(ulonglong2*)(Al + row * LROW + g * 16) = va;
        ulonglong2 vb = *(const ulonglong2*)((const char*)(cb + (size_t)(bj + row) * FEAT) + g * 16);
        *(ulonglong2*)(Bl + row * LROW + g * 16) = vb;
    }
    __syncthreads();

    const int lane = t & 63;
    const int wave = t >> 6;
    const int wr = (wave >> 1) * 64;
    const int wc = (wave & 1) * 64;
    const int l15 = lane & 15, quad = lane >> 4;

    f32x4 acc[4][4];
    #pragma unroll
    for (int i = 0; i < 4; ++i)
        #pragma unroll
        for (int j = 0; j < 4; ++j)
            acc[i][j] = (f32x4){0.f, 0.f, 0.f, 0.f};

    #pragma unroll
    for (int ks = 0; ks < 4; ++ks) {
        bf16x8 a[4], b[4];
        #pragma unroll
        for (int s = 0; s < 4; ++s) {
            a[s] = *(const bf16x8*)(Al + (wr + s * 16 + l15) * LROW + ks * 64 + quad * 16);
            b[s] = *(const bf16x8*)(Bl + (wc + s * 16 + l15) * LROW + ks * 64 + quad * 16);
        }
        #pragma unroll
        for (int si = 0; si < 4; ++si)
            #pragma unroll
            for (int sj = 0; sj < 4; ++sj)
                acc[si][sj] = __builtin_amdgcn_mfma_f32_16x16x32_bf16(a[si], b[sj], acc[si][sj], 0, 0, 0);
    }

    // epilogue: C-layout -> LDS tile (bit-identical math), then coalesced store
    float c2v[4];
    #pragma unroll
    for (int sj = 0; sj < 4; ++sj) c2v[sj] = c2g[bj + wc + sj * 16 + l15];
    __syncthreads();                         // all waves done reading A/B LDS
    float* tile = (float*)lds;               // 128 x TROW f32 (67.6 KB)
    #pragma unroll
    for (int si = 0; si < 4; ++si) {
        #pragma unroll
        for (int r = 0; r < 4; ++r) {
            int mloc = wr + si * 16 + quad * 4 + r;
            float xv = x2g[bi + mloc];
            #pragma unroll
            for (int sj = 0; sj < 4; ++sj) {
                float v = fmaxf(xv + c2v[sj] - 2.0f * acc[si][sj][r], 0.0f);
                tile[mloc * TROW + wc + sj * 16 + l15] = v;
            }
        }
    }
    __syncthreads();
    #pragma unroll
    for (int i = 0; i < 16; ++i) {
        int s4  = t + i * 256;               // 4096 float4 slots
        int row = s4 >> 5;                   // 32 float4 per row
        int c4  = (s4 & 31) * 4;
        float4 v = *(const float4*)&tile[row * TROW + c4];
        *(float4*)(d2 + (size_t)(bi + row) * N_CVS + bj + c4) = v;
    }
}

// ---------------- top-15 per row: exact threshold-filter + knockout ---------
// __launch_bounds__(256,3): pin 12 waves/CU but allow ~170 VGPR so the whole
// 16xfloat4 row stays live (default bounds gave 56 VGPR -> forced re-reads).
__global__ __launch_bounds__(256, 3) void topk_kernel(const float* __restrict__ d2,
                                                      int* __restrict__ knn) {
    __shared__ unsigned long long cand[4][64];
    const int wv   = threadIdx.x >> 6;
    const int wid  = blockIdx.x * 4 + wv;
    const int lane = threadIdx.x & 63;
    const float* row = d2 + (size_t)wid * N_CVS;

    float4 v[16];
    #pragma unroll
    for (int i = 0; i < 16; ++i)
        v[i] = *(const float4*)(row + lane * 4 + i * 256);

    float mn = fminf(fminf(v[0].x, v[0].y), fminf(v[0].z, v[0].w));
    #pragma unroll
    for (int i = 1; i < 16; ++i)
        mn = fminf(mn, fminf(fminf(v[i].x, v[i].y), fminf(v[i].z, v[i].w)));

    float s = mn;
    #pragma unroll
    for (int k = 2; k <= 64; k <<= 1) {
        #pragma unroll
        for (int j = k >> 1; j > 0; j >>= 1) {
            float o = __shfl_xor(s, j, 64);
            bool lower = ((lane & j) == 0);
            bool asc   = ((lane & k) == 0);
            float lo = fminf(s, o), hi = fmaxf(s, o);
            s = (lower == asc) ? lo : hi;
        }
    }
    float T = __shfl(s, 15, 64);

    unsigned long long* cbuf = cand[wv];
    int base = 0;
    #pragma unroll
    for (int i = 0; i < 16; ++i) {
        float vv[4] = {v[i].x, v[i].y, v[i].z, v[i].w};
        #pragma unroll
        for (int c = 0; c < 4; ++c) {
            bool p = (vv[c] <= T);
            unsigned long long mask = __ballot(p);
            if (p) {
                int pos = base + __popcll(mask & ((1ULL << lane) - 1ULL));
                if (pos < 64)
                    cbuf[pos] = ((unsigned long long)__float_as_uint(vv[c]) << 32)
                              | (unsigned)(lane * 4 + i * 256 + c);
            }
            base += __popcll(mask);
        }
    }
    __builtin_amdgcn_wave_barrier();

    int* outp = knn + wid * KNN_K;
    if (base <= 64) {
        unsigned long long key = (lane < base) ? cbuf[lane] : ~0ULL;
        for (int r = 0; r < KNN_K; ++r) {
            unsigned long long m = key;
            #pragma unroll
            for (int off = 32; off > 0; off >>= 1) {
                unsigned long long o = __shfl_xor(m, off, 64);
                m = (o < m) ? o : m;
            }
            if (lane == 0) outp[r] = (int)(unsigned)(m & 0xffffffffu);
            if (key == m) key = ~0ULL;
        }
    } else {
        unsigned long long heap[15];
        #pragma unroll
        for (int k = 0; k < 15; ++k) heap[k] = ~0ULL;
        for (int i = 0; i < 16; ++i) {
            int j0 = lane * 4 + i * 256;
            float4 f4 = *(const float4*)(row + j0);
            float vv[4] = {f4.x, f4.y, f4.z, f4.w};
            #pragma unroll
            for (int c = 0; c < 4; ++c) {
                unsigned long long key =
                    ((unsigned long long)__float_as_uint(vv[c]) << 32) | (unsigned)(j0 + c);
                if (key < heap[14]) {
                    heap[14] = key;
                    #pragma unroll
                    for (int k = 14; k > 0; --k) {
                        unsigned long long a = heap[k-1], b = heap[k];
                        bool sw = b < a;
                        heap[k-1] = sw ? b : a;
                        heap[k]   = sw ? a : b;
                    }
                }
            }
        }
        for (int r = 0; r < KNN_K; ++r) {
            unsigned long long cd = heap[0];
            unsigned long long m = cd;
            #pragma unroll
            for (int off = 32; off > 0; off >>= 1) {
                unsigned long long o = __shfl_xor(m, off, 64);
                m = (o < m) ? o : m;
            }
            if (lane == 0) outp[r] = (int)(unsigned)(m & 0xffffffffu);
            if (cd == m) {
                #pragma unroll
                for (int k = 0; k < 14; ++k) heap[k] = heap[k+1];
                heap[14] = ~0ULL;
            }
        }
    }
}

// ---------------- visits + cce scatter (cce packed u8, word atomics) --------
__global__ void scatter_kernel(const int* __restrict__ knn, int* __restrict__ visits,
                               unsigned int* __restrict__ cce8) {
    int b = blockIdx.x * 256 + threadIdx.x;
    const int* kr = knn + b * KNN_K;
    int closest = kr[0];
    atomicAdd(&visits[closest], 1);
    size_t base = (size_t)closest * N_CVS;
    #pragma unroll
    for (int k = 0; k < KNN_K; ++k) {
        size_t idx = base + kr[k];
        atomicAdd((int*)&cce8[idx >> 2], 1 << ((idx & 3) * 8));
    }
}

// ---------------- neighbor mask bits: one block per row, 16 elems/thread ----
// enc<=9 integer rule: np computes 0.9f**enc in fp32; 0.9f^10 < E_MIN, so
// enc==10 edges are dropped by the reference (verified absmax 0.0 in R8).
// conn loaded conditionally (~0.8% density).
__global__ __launch_bounds__(256) void bits_kernel(
        const unsigned int* __restrict__ cce8, const int* __restrict__ visits,
        const float* __restrict__ edges, const float* __restrict__ conn,
        unsigned short* __restrict__ bits16) {
    const int row = blockIdx.x;
    const int t   = threadIdx.x;
    const int vis = visits[row];
    size_t eb = (size_t)row * N_CVS + t * 16;
    f32x4 e[4];
    #pragma unroll
    for (int q = 0; q < 4; ++q) e[q] = ((const f32x4*)(edges + eb))[q];
    u32x4 cw = ((const u32x4*)(cce8 + (size_t)row * 1024))[t];

    unsigned pre = 0;
    #pragma unroll
    for (int q = 0; q < 4; ++q) {
        #pragma unroll
        for (int s = 0; s < 4; ++s) {
            int cc = (cw[q] >> (s * 8)) & 0xff;
            float ev = e[q][s];
            float ex = (cc > 0) ? fmaxf(ev, 1.0f) : ev;
            bool p;
            if (ex == 1.0f) {
                p = (vis - cc) <= 9;
            } else if (ex > 0.0f) {
                float enc = fmaxf((float)(vis - cc), 0.0f);
                p = ex * powf(0.9f, enc) >= E_MIN_F;
            } else {
                p = false;
            }
            pre |= (unsigned)p << (q * 4 + s);
        }
    }
    unsigned m = 0;
    #pragma unroll
    for (int q = 0; q < 4; ++q) {
        unsigned pn = (pre >> (q * 4)) & 0xfu;
        if (pn) {
            f32x4 cv = ((const f32x4*)(conn + eb))[q];
            #pragma unroll
            for (int s = 0; s < 4; ++s)
                if (((pn >> s) & 1u) && (cv[s] < 1.0f)) m |= 1u << (q * 4 + s);
        }
    }
    bits16[(size_t)row * 256 + t] = (unsigned short)m;
}

// ---------------- per-sample masked soft-min loss -> partial[b] -------------
__global__ void loss_kernel(const float* __restrict__ d2,
                            const unsigned long long* __restrict__ bits,
                            const int* __restrict__ labels, float* __restrict__ partial) {
    int wid  = blockIdx.x * 4 + (threadIdx.x >> 6);
    int lane = threadIdx.x & 63;
    int l = labels[wid];
    const unsigned long long* rb = bits + (size_t)l * 64;
    const float* row = d2 + (size_t)wid * N_CVS;
    float se = 0.f, sed = 0.f;
    unsigned long long w = rb[lane];
    while (w) {
        int c = __builtin_ctzll(w);
        w &= w - 1;
        int j = lane * 64 + c;
        float d = row[j];
        if (d > 0.f) {
            float ee = __expf(-0.001f * d);
            se += ee; sed += ee * d;
        }
    }
    #pragma unroll
    for (int off = 32; off > 0; off >>= 1) {
        se  += __shfl_xor(se,  off, 64);
        sed += __shfl_xor(sed, off, 64);
    }
    if (lane == 0) {
        float dpos = row[l];
        float wsum = se > 0.f ? sed / se : 0.f;
        float mu = dpos - wsum;
        partial[wid] = (mu > 0.f) ? mu : 0.f;
    }
}

// ---------------- final reduction: sum(partial)/BATCH -> out ----------------
__global__ void reduce_kernel(const float* __restrict__ partial, float* __restrict__ out) {
    int t = threadIdx.x;
    float s = 0.f;
    #pragma unroll
    for (int i = 0; i < BATCH / 256; ++i) s += partial[t + i * 256];
    #pragma unroll
    for (int off = 32; off > 0; off >>= 1) s += __shfl_xor(s, off, 64);
    __shared__ float wsum[4];
    if ((t & 63) == 0) wsum[t >> 6] = s;
    __syncthreads();
    if (t == 0) out[0] = (wsum[0] + wsum[1] + wsum[2] + wsum[3]) * (1.0f / BATCH);
}

extern "C" void kernel_launch(void* const* d_in, const int* in_sizes, int n_in,
                              void* d_out, int out_size, void* d_ws, size_t ws_size,
                              hipStream_t stream) {
    const float* x      = (const float*)d_in[0];
    const float* cvs    = (const float*)d_in[1];
    const float* edges  = (const float*)d_in[2];
    const float* conn   = (const float*)d_in[3];
    const int*   labels = (const int*)d_in[4];

    char* p = (char*)d_ws;
    float* d2 = (float*)p;                  p += (size_t)BATCH * N_CVS * 4;   // 128 MB
    int* knn  = (int*)p;                    p += (size_t)BATCH * KNN_K * 4;   // 480 KB
    int* visits = (int*)p;                  p += (size_t)N_CVS * 4;           // 16 KB
    unsigned int* cce8 = (unsigned int*)p;  p += (size_t)N_CVS * N_CVS;       // 16 MB (u8)
    unsigned long long* bits = (unsigned long long*)p;
                                            p += (size_t)N_CVS * 64 * 8;      // 2 MB
    float* x2 = (float*)p;                  p += (size_t)BATCH * 4;
    float* c2 = (float*)p;                  p += (size_t)N_CVS * 4;
    unsigned short* xb = (unsigned short*)p; p += (size_t)BATCH * FEAT * 2;   // 2 MB
    unsigned short* cb = (unsigned short*)p; p += (size_t)N_CVS * FEAT * 2;   // 1 MB
    float* partial = (float*)p;             p += (size_t)BATCH * 4;           // 32 KB

    hipMemsetAsync(visits, 0, (size_t)N_CVS * 4 + (size_t)N_CVS * N_CVS, stream);

    cvtnorm_kernel<<<(BATCH + N_CVS) * FEAT / 8 / 256, 256, 0, stream>>>(x, cvs, xb, cb, x2, c2);
    mfma_d2_kernel<<<dim3(N_CVS / 128, BATCH / 128), 256, 0, stream>>>(xb, cb, x2, c2, d2);
    topk_kernel   <<<BATCH / 4, 256, 0, stream>>>(d2, knn);
    scatter_kernel<<<BATCH / 256, 256, 0, stream>>>(knn, visits, cce8);
    bits_kernel   <<<N_CVS, 256, 0, stream>>>(
                      cce8, visits, edges, conn, (unsigned short*)bits);
    loss_kernel   <<<BATCH / 4, 256, 0, stream>>>(d2, bits, labels, partial);
    reduce_kernel <<<1, 256, 0, stream>>>(partial, (float*)d_out);
}

// Round 12
// 218.279 us; speedup vs baseline: 1.0961x; 1.0491x over previous
//
#include <hip/hip_runtime.h>
#include <math.h>

#define N_CVS   4096
#define FEAT    128
#define BATCH   8192
#define KNN_K   15
#define E_MIN_F 0.34867844f

typedef __attribute__((ext_vector_type(8))) short bf16x8;
typedef __attribute__((ext_vector_type(4))) float f32x4;
typedef __attribute__((ext_vector_type(4))) unsigned int u32x4;

// ------- fused fp32->bf16 (RNE) + row norms (16 threads/row, shfl reduce) ---
__global__ void cvtnorm_kernel(const float* __restrict__ x, const float* __restrict__ cvs,
                               unsigned short* __restrict__ xb, unsigned short* __restrict__ cb,
                               float* __restrict__ x2, float* __restrict__ c2) {
    size_t tid = (size_t)blockIdx.x * 256 + threadIdx.x;
    size_t f = tid * 8;
    const float* src; unsigned short* dst; float* ndst; size_t row;
    if (f < (size_t)BATCH * FEAT) { src = x + f; dst = xb + f; row = f >> 7; ndst = x2 + row; }
    else {
        size_t g = f - (size_t)BATCH * FEAT;
        src = cvs + g; dst = cb + g; row = g >> 7; ndst = c2 + row;
    }
    float4 v0 = ((const float4*)src)[0];
    float4 v1 = ((const float4*)src)[1];
    float vv[8] = {v0.x, v0.y, v0.z, v0.w, v1.x, v1.y, v1.z, v1.w};
    bf16x8 o;
    float s = 0.f;
    #pragma unroll
    for (int i = 0; i < 8; ++i) {
        unsigned u = __float_as_uint(vv[i]);
        o[i] = (short)((u + 0x7fffu + ((u >> 16) & 1u)) >> 16);   // RNE
        s += vv[i] * vv[i];
    }
    *(bf16x8*)dst = o;
    #pragma unroll
    for (int off = 1; off < 16; off <<= 1) s += __shfl_xor(s, off, 64);
    if ((threadIdx.x & 15) == 0) *ndst = s;
}

// ---------------- d2 = max(x2 + c2 - 2 x.cv^T, 0), bf16 MFMA ----------------
// Epilogue stages the 128x128 f32 tile through LDS (reusing the A/B buffers,
// +4 col pad -> 2-way bank aliasing only) so global stores are coalesced
// dwordx4 (direct C-layout store measured 3.6 TB/s in R10 = store-bound).
#define LROW 272
#define TROW 132
__global__ __launch_bounds__(256) void mfma_d2_kernel(
        const unsigned short* __restrict__ xb, const unsigned short* __restrict__ cb,
        const float* __restrict__ x2g, const float* __restrict__ c2g,
        float* __restrict__ d2) {
    __shared__ __align__(16) char lds[2 * 128 * LROW];   // 68 KB
    char* Al = lds;
    char* Bl = lds + 128 * LROW;
    const int bi = blockIdx.y * 128;
    const int bj = blockIdx.x * 128;
    const int t  = threadIdx.x;

    #pragma unroll
    for (int i = 0; i < 8; ++i) {
        int f = t + i * 256;
        int row = f >> 4, g = f & 15;
        ulonglong2 va = *(const ulonglong2*)((const char*)(xb + (size_t)(bi + row) * FEAT) + g * 16);
        *(ulonglong2*)(Al + row * LROW + g * 16) = va;
        ulonglong2 vb = *(const ulonglong2*)((const char*)(cb + (size_t)(bj + row) * FEAT) + g * 16);
        *(ulonglong2*)(Bl + row * LROW + g * 16) = vb;
    }
    __syncthreads();

    const int lane = t & 63;
    const int wave = t >> 6;
    const int wr = (wave >> 1) * 64;
    const int wc = (wave & 1) * 64;
    const int l15 = lane & 15, quad = lane >> 4;

    f32x4 acc[4][4];
    #pragma unroll
    for (int i = 0; i < 4; ++i)
        #pragma unroll
        for (int j = 0; j < 4; ++j)
            acc[i][j] = (f32x4){0.f, 0.f, 0.f, 0.f};

    #pragma unroll
    for (int ks = 0; ks < 4; ++ks) {
        bf16x8 a[4], b[4];
        #pragma unroll
        for (int s = 0; s < 4; ++s) {
            a[s] = *(const bf16x8*)(Al + (wr + s * 16 + l15) * LROW + ks * 64 + quad * 16);
            b[s] = *(const bf16x8*)(Bl + (wc + s * 16 + l15) * LROW + ks * 64 + quad * 16);
        }
        #pragma unroll
        for (int si = 0; si < 4; ++si)
            #pragma unroll
            for (int sj = 0; sj < 4; ++sj)
                acc[si][sj] = __builtin_amdgcn_mfma_f32_16x16x32_bf16(a[si], b[sj], acc[si][sj], 0, 0, 0);
    }

    float c2v[4];
    #pragma unroll
    for (int sj = 0; sj < 4; ++sj) c2v[sj] = c2g[bj + wc + sj * 16 + l15];
    __syncthreads();                         // all waves done reading A/B LDS
    float* tile = (float*)lds;               // 128 x TROW f32 (67.6 KB)
    #pragma unroll
    for (int si = 0; si < 4; ++si) {
        #pragma unroll
        for (int r = 0; r < 4; ++r) {
            int mloc = wr + si * 16 + quad * 4 + r;
            float xv = x2g[bi + mloc];
            #pragma unroll
            for (int sj = 0; sj < 4; ++sj) {
                float v = fmaxf(xv + c2v[sj] - 2.0f * acc[si][sj][r], 0.0f);
                tile[mloc * TROW + wc + sj * 16 + l15] = v;
            }
        }
    }
    __syncthreads();
    #pragma unroll
    for (int i = 0; i < 16; ++i) {
        int s4  = t + i * 256;               // 4096 float4 slots
        int row = s4 >> 5;                   // 32 float4 per row
        int c4  = (s4 & 31) * 4;
        float4 v = *(const float4*)&tile[row * TROW + c4];
        *(float4*)(d2 + (size_t)(bi + row) * N_CVS + bj + c4) = v;
    }
}

// ------- top-15 per row (exact threshold-filter + knockout) + fused scatter -
// Winners live in lane-0 registers after the knockout, so visits/cce8 atomics
// issue directly from here (removes the scatter dispatch + knn round-trip).
// __launch_bounds__(256,3): 12 waves/CU, ~170 VGPR so the 16xfloat4 row stays
// live (default bounds gave 56 VGPR -> forced re-reads, 49us at 1.4 TB/s).
__global__ __launch_bounds__(256, 3) void topk_kernel(const float* __restrict__ d2,
                                                      int* __restrict__ visits,
                                                      unsigned int* __restrict__ cce8) {
    __shared__ unsigned long long cand[4][64];
    const int wv   = threadIdx.x >> 6;
    const int wid  = blockIdx.x * 4 + wv;
    const int lane = threadIdx.x & 63;
    const float* row = d2 + (size_t)wid * N_CVS;

    float4 v[16];
    #pragma unroll
    for (int i = 0; i < 16; ++i)
        v[i] = *(const float4*)(row + lane * 4 + i * 256);

    float mn = fminf(fminf(v[0].x, v[0].y), fminf(v[0].z, v[0].w));
    #pragma unroll
    for (int i = 1; i < 16; ++i)
        mn = fminf(mn, fminf(fminf(v[i].x, v[i].y), fminf(v[i].z, v[i].w)));

    float s = mn;
    #pragma unroll
    for (int k = 2; k <= 64; k <<= 1) {
        #pragma unroll
        for (int j = k >> 1; j > 0; j >>= 1) {
            float o = __shfl_xor(s, j, 64);
            bool lower = ((lane & j) == 0);
            bool asc   = ((lane & k) == 0);
            float lo = fminf(s, o), hi = fmaxf(s, o);
            s = (lower == asc) ? lo : hi;
        }
    }
    float T = __shfl(s, 15, 64);

    unsigned long long* cbuf = cand[wv];
    int base = 0;
    #pragma unroll
    for (int i = 0; i < 16; ++i) {
        float vv[4] = {v[i].x, v[i].y, v[i].z, v[i].w};
        #pragma unroll
        for (int c = 0; c < 4; ++c) {
            bool p = (vv[c] <= T);
            unsigned long long mask = __ballot(p);
            if (p) {
                int pos = base + __popcll(mask & ((1ULL << lane) - 1ULL));
                if (pos < 64)
                    cbuf[pos] = ((unsigned long long)__float_as_uint(vv[c]) << 32)
                              | (unsigned)(lane * 4 + i * 256 + c);
            }
            base += __popcll(mask);
        }
    }
    __builtin_amdgcn_wave_barrier();

    int knnv[KNN_K];
    if (base <= 64) {
        unsigned long long key = (lane < base) ? cbuf[lane] : ~0ULL;
        #pragma unroll
        for (int r = 0; r < KNN_K; ++r) {
            unsigned long long m = key;
            #pragma unroll
            for (int off = 32; off > 0; off >>= 1) {
                unsigned long long o = __shfl_xor(m, off, 64);
                m = (o < m) ? o : m;
            }
            knnv[r] = (int)(unsigned)(m & 0xffffffffu);
            if (key == m) key = ~0ULL;
        }
    } else {
        // exact fallback (pathological data only): full 15-deep insertion scan
        unsigned long long heap[15];
        #pragma unroll
        for (int k = 0; k < 15; ++k) heap[k] = ~0ULL;
        for (int i = 0; i < 16; ++i) {
            int j0 = lane * 4 + i * 256;
            float4 f4 = *(const float4*)(row + j0);
            float vv[4] = {f4.x, f4.y, f4.z, f4.w};
            #pragma unroll
            for (int c = 0; c < 4; ++c) {
                unsigned long long key =
                    ((unsigned long long)__float_as_uint(vv[c]) << 32) | (unsigned)(j0 + c);
                if (key < heap[14]) {
                    heap[14] = key;
                    #pragma unroll
                    for (int k = 14; k > 0; --k) {
                        unsigned long long a = heap[k-1], b = heap[k];
                        bool sw = b < a;
                        heap[k-1] = sw ? b : a;
                        heap[k]   = sw ? a : b;
                    }
                }
            }
        }
        #pragma unroll
        for (int r = 0; r < KNN_K; ++r) {
            unsigned long long cd = heap[0];
            unsigned long long m = cd;
            #pragma unroll
            for (int off = 32; off > 0; off >>= 1) {
                unsigned long long o = __shfl_xor(m, off, 64);
                m = (o < m) ? o : m;
            }
            knnv[r] = (int)(unsigned)(m & 0xffffffffu);
            if (cd == m) {
                #pragma unroll
                for (int k = 0; k < 14; ++k) heap[k] = heap[k+1];
                heap[14] = ~0ULL;
            }
        }
    }

    // fused scatter: lane 0 owns the winners
    if (lane == 0) {
        int closest = knnv[0];
        atomicAdd(&visits[closest], 1);
        size_t cbase = (size_t)closest * N_CVS;
        #pragma unroll
        for (int k = 0; k < KNN_K; ++k) {
            size_t idx = cbase + knnv[k];
            atomicAdd((int*)&cce8[idx >> 2], 1 << ((idx & 3) * 8));
        }
    }
}

// ---------------- neighbor mask bits: one block per row, 16 elems/thread ----
// enc<=9 integer rule: np computes 0.9f**enc in fp32; 0.9f^10 < E_MIN, so
// enc==10 edges are dropped by the reference (verified absmax 0.0 in R8).
// conn loaded conditionally (~0.8% density).
__global__ __launch_bounds__(256) void bits_kernel(
        const unsigned int* __restrict__ cce8, const int* __restrict__ visits,
        const float* __restrict__ edges, const float* __restrict__ conn,
        unsigned short* __restrict__ bits16) {
    const int row = blockIdx.x;
    const int t   = threadIdx.x;
    const int vis = visits[row];
    size_t eb = (size_t)row * N_CVS + t * 16;
    f32x4 e[4];
    #pragma unroll
    for (int q = 0; q < 4; ++q) e[q] = ((const f32x4*)(edges + eb))[q];
    u32x4 cw = ((const u32x4*)(cce8 + (size_t)row * 1024))[t];

    unsigned pre = 0;
    #pragma unroll
    for (int q = 0; q < 4; ++q) {
        #pragma unroll
        for (int s = 0; s < 4; ++s) {
            int cc = (cw[q] >> (s * 8)) & 0xff;
            float ev = e[q][s];
            float ex = (cc > 0) ? fmaxf(ev, 1.0f) : ev;
            bool p;
            if (ex == 1.0f) {
                p = (vis - cc) <= 9;
            } else if (ex > 0.0f) {
                float enc = fmaxf((float)(vis - cc), 0.0f);
                p = ex * powf(0.9f, enc) >= E_MIN_F;
            } else {
                p = false;
            }
            pre |= (unsigned)p << (q * 4 + s);
        }
    }
    unsigned m = 0;
    #pragma unroll
    for (int q = 0; q < 4; ++q) {
        unsigned pn = (pre >> (q * 4)) & 0xfu;
        if (pn) {
            f32x4 cv = ((const f32x4*)(conn + eb))[q];
            #pragma unroll
            for (int s = 0; s < 4; ++s)
                if (((pn >> s) & 1u) && (cv[s] < 1.0f)) m |= 1u << (q * 4 + s);
        }
    }
    bits16[(size_t)row * 256 + t] = (unsigned short)m;
}

// ---------------- per-sample masked soft-min loss -> partial[b] -------------
__global__ void loss_kernel(const float* __restrict__ d2,
                            const unsigned long long* __restrict__ bits,
                            const int* __restrict__ labels, float* __restrict__ partial) {
    int wid  = blockIdx.x * 4 + (threadIdx.x >> 6);
    int lane = threadIdx.x & 63;
    int l = labels[wid];
    const unsigned long long* rb = bits + (size_t)l * 64;
    const float* row = d2 + (size_t)wid * N_CVS;
    float se = 0.f, sed = 0.f;
    unsigned long long w = rb[lane];
    while (w) {
        int c = __builtin_ctzll(w);
        w &= w - 1;
        int j = lane * 64 + c;
        float d = row[j];
        if (d > 0.f) {
            float ee = __expf(-0.001f * d);
            se += ee; sed += ee * d;
        }
    }
    #pragma unroll
    for (int off = 32; off > 0; off >>= 1) {
        se  += __shfl_xor(se,  off, 64);
        sed += __shfl_xor(sed, off, 64);
    }
    if (lane == 0) {
        float dpos = row[l];
        float wsum = se > 0.f ? sed / se : 0.f;
        float mu = dpos - wsum;
        partial[wid] = (mu > 0.f) ? mu : 0.f;
    }
}

// ---------------- final reduction: sum(partial)/BATCH -> out ----------------
__global__ void reduce_kernel(const float* __restrict__ partial, float* __restrict__ out) {
    int t = threadIdx.x;
    float s = 0.f;
    #pragma unroll
    for (int i = 0; i < BATCH / 256; ++i) s += partial[t + i * 256];
    #pragma unroll
    for (int off = 32; off > 0; off >>= 1) s += __shfl_xor(s, off, 64);
    __shared__ float wsum[4];
    if ((t & 63) == 0) wsum[t >> 6] = s;
    __syncthreads();
    if (t == 0) out[0] = (wsum[0] + wsum[1] + wsum[2] + wsum[3]) * (1.0f / BATCH);
}

extern "C" void kernel_launch(void* const* d_in, const int* in_sizes, int n_in,
                              void* d_out, int out_size, void* d_ws, size_t ws_size,
                              hipStream_t stream) {
    const float* x      = (const float*)d_in[0];
    const float* cvs    = (const float*)d_in[1];
    const float* edges  = (const float*)d_in[2];
    const float* conn   = (const float*)d_in[3];
    const int*   labels = (const int*)d_in[4];

    char* p = (char*)d_ws;
    float* d2 = (float*)p;                  p += (size_t)BATCH * N_CVS * 4;   // 128 MB
    int* visits = (int*)p;                  p += (size_t)N_CVS * 4;           // 16 KB
    unsigned int* cce8 = (unsigned int*)p;  p += (size_t)N_CVS * N_CVS;       // 16 MB (u8)
    unsigned long long* bits = (unsigned long long*)p;
                                            p += (size_t)N_CVS * 64 * 8;      // 2 MB
    float* x2 = (float*)p;                  p += (size_t)BATCH * 4;
    float* c2 = (float*)p;                  p += (size_t)N_CVS * 4;
    unsigned short* xb = (unsigned short*)p; p += (size_t)BATCH * FEAT * 2;   // 2 MB
    unsigned short* cb = (unsigned short*)p; p += (size_t)N_CVS * FEAT * 2;   // 1 MB
    float* partial = (float*)p;             p += (size_t)BATCH * 4;           // 32 KB

    // zero visits + cce8 (contiguous)
    hipMemsetAsync(visits, 0, (size_t)N_CVS * 4 + (size_t)N_CVS * N_CVS, stream);

    cvtnorm_kernel<<<(BATCH + N_CVS) * FEAT / 8 / 256, 256, 0, stream>>>(x, cvs, xb, cb, x2, c2);
    mfma_d2_kernel<<<dim3(N_CVS / 128, BATCH / 128), 256, 0, stream>>>(xb, cb, x2, c2, d2);
    topk_kernel   <<<BATCH / 4, 256, 0, stream>>>(d2, visits, cce8);
    bits_kernel   <<<N_CVS, 256, 0, stream>>>(
                      cce8, visits, edges, conn, (unsigned short*)bits);
    loss_kernel   <<<BATCH / 4, 256, 0, stream>>>(d2, bits, labels, partial);
    reduce_kernel <<<1, 256, 0, stream>>>(partial, (float*)d_out);
}